// Round 12
// baseline (1125.342 us; speedup 1.0000x reference)
//
#include <hip/hip_runtime.h>
#include <hip/hip_bf16.h>

// Model dims: B=256, T=256, F=512, H=512, DIN=17 (padded to 32 in seq concat)
#define EPSK 1e-3f

using bf16x8 = __attribute__((ext_vector_type(8))) short;
using s16x4  = __attribute__((ext_vector_type(4))) short;
using f32x4  = __attribute__((ext_vector_type(4))) float;
using u32x2  = __attribute__((ext_vector_type(2))) unsigned int;

__device__ __forceinline__ float bf2f(short s) {
    union { unsigned u; float f; } x; x.u = ((unsigned)(unsigned short)s) << 16; return x.f;
}
__device__ __forceinline__ unsigned short f2bfu(float f) {
    union { float f; unsigned u; } x; x.f = f;
    unsigned r = x.u + 0x7fffu + ((x.u >> 16) & 1u);   // RNE
    return (unsigned short)(r >> 16);
}
__device__ __forceinline__ float sigm(float x) { return 1.0f / (1.0f + __expf(-x)); }
__device__ __forceinline__ float ftanh(float x) {
    float e = __expf(2.0f * x);
    return 1.0f - 2.0f / (e + 1.0f);
}

// device-coherent (LLC) ops — bypass XCD-local caches (R6-proven)
__device__ __forceinline__ f32x4 load16_coh(const void* p) {
    f32x4 v;
    asm volatile("global_load_dwordx4 %0, %1, off sc0 sc1" : "=v"(v) : "v"(p) : "memory");
    return v;
}
__device__ __forceinline__ void store8_coh(void* p, u32x2 v) {
    asm volatile("global_store_dwordx2 %0, %1, off sc0 sc1" :: "v"(p), "v"(v) : "memory");
}
__device__ __forceinline__ void store8_nt(void* p, u32x2 v) {
    asm volatile("global_store_dwordx2 %0, %1, off nt" :: "v"(p), "v"(v) : "memory");
}

// ---------------- utility kernels ----------------

__global__ void cvt_f2b_kernel(__hip_bfloat16* __restrict__ dst, const float* __restrict__ src, int n)
{
    for (int i = blockIdx.x * blockDim.x + threadIdx.x; i < n; i += gridDim.x * blockDim.x)
        dst[i] = __float2bfloat16(src[i]);
}

__global__ void copy_f_kernel(float* __restrict__ dst, const float* __restrict__ src, int n)
{
    for (int i = blockIdx.x * blockDim.x + threadIdx.x; i < n; i += gridDim.x * blockDim.x)
        dst[i] = src[i];
}

// batched tiled transpose: dst[n][kOff+k](bf16, stride KD) = src[k][n] (f32 [K][N])
#define NTJOBS 11
struct TransJobs {
    const float* src[NTJOBS];
    __hip_bfloat16* dst[NTJOBS];
    int K[NTJOBS], N[NTJOBS], kOff[NTJOBS], KD[NTJOBS];
};

__global__ __launch_bounds__(256)
void trans_tiled_kernel(TransJobs jobs)
{
    const int j = blockIdx.y;
    const int K = jobs.K[j], N = jobs.N[j];
    const int tilesN = (N + 31) >> 5;
    const int tilesK = (K + 31) >> 5;
    if ((int)blockIdx.x >= tilesN * tilesK) return;
    const int tk = blockIdx.x / tilesN, tn = blockIdx.x % tilesN;
    const int kOff = jobs.kOff[j], KD = jobs.KD[j];
    const float* src = jobs.src[j];
    __hip_bfloat16* dst = jobs.dst[j];
    __shared__ float tile[32][33];
    const int tid = threadIdx.x;
    #pragma unroll
    for (int i = 0; i < 4; ++i) {
        int e = i * 256 + tid;
        int r = e >> 5, c = e & 31;
        int k = tk * 32 + r, n = tn * 32 + c;
        tile[r][c] = (k < K && n < N) ? src[(size_t)k * N + n] : 0.f;
    }
    __syncthreads();
    #pragma unroll
    for (int i = 0; i < 4; ++i) {
        int e = i * 256 + tid;
        int rn = e >> 5, ck = e & 31;
        int n = tn * 32 + rn, k = tk * 32 + ck;
        if (k < K && n < N) dst[(size_t)n * KD + kOff + k] = __float2bfloat16(tile[ck][rn]);
    }
}

// ---------------- funnel: LN + MLP(MFMA stages 1-2) + BN -> seq_bf [T][B][32] ----------------

__global__ __launch_bounds__(256)
void funnel_kernel(const float* __restrict__ x, const int* __restrict__ yp,
                   const float* __restrict__ ln_g, const float* __restrict__ ln_b,
                   const __hip_bfloat16* __restrict__ w1T,  // [128][512] bf16
                   const float* __restrict__ b1,
                   const __hip_bfloat16* __restrict__ w2T,  // [64][128] bf16
                   const float* __restrict__ b2,
                   const float* __restrict__ w3, const float* __restrict__ b3,
                   const float* __restrict__ w4, const float* __restrict__ b4,
                   const float* __restrict__ bn1g, const float* __restrict__ bn1b,
                   const float* __restrict__ bn1m, const float* __restrict__ bn1v,
                   const float* __restrict__ bn2g, const float* __restrict__ bn2b,
                   const float* __restrict__ bn2m, const float* __restrict__ bn2v,
                   __hip_bfloat16* __restrict__ seqbf)
{
    __shared__ __align__(16) __hip_bfloat16 xn[16][520];   // 1040B row = 65x16B
    __shared__ __align__(16) __hip_bfloat16 h1s[16][136];  // 272B row = 17x16B
    __shared__ float h2s[16][64];
    __shared__ float h3s[16][32];
    const int tid = threadIdx.x;
    const int w = tid >> 6, lane = tid & 63;
    const int l15 = lane & 15, l4 = lane >> 4;
    const int g0 = blockIdx.x * 16;

    for (int pp = 0; pp < 4; ++pp) {
        int r = pp * 4 + w;
        const float* xr = x + (size_t)(g0 + r) * 512;
        f32x4 v0 = *(const f32x4*)(xr + lane * 8);
        f32x4 v1 = *(const f32x4*)(xr + lane * 8 + 4);
        float s = v0[0]+v0[1]+v0[2]+v0[3] + v1[0]+v1[1]+v1[2]+v1[3];
        float q = v0[0]*v0[0]+v0[1]*v0[1]+v0[2]*v0[2]+v0[3]*v0[3]
                + v1[0]*v1[0]+v1[1]*v1[1]+v1[2]*v1[2]+v1[3]*v1[3];
        for (int o = 32; o; o >>= 1) { s += __shfl_xor(s, o); q += __shfl_xor(q, o); }
        float mu = s * (1.0f / 512.0f);
        float var = q * (1.0f / 512.0f) - mu * mu;
        float rs = rsqrtf(var + EPSK);
        union { unsigned short s[8]; f32x4 v; } pk;
        #pragma unroll
        for (int j = 0; j < 8; ++j) {
            int c = lane * 8 + j;
            float xv = (j < 4) ? v0[j] : v1[j - 4];
            pk.s[j] = f2bfu((xv - mu) * rs * ln_g[c] + ln_b[c]);
        }
        *(f32x4*)(&xn[r][lane * 8]) = pk.v;
    }
    __syncthreads();

    // stage1 (MFMA): 512 -> 128, relu, bn1 -> h1s bf16
    {
        f32x4 acc[2];
        acc[0] = (f32x4){0.f,0.f,0.f,0.f};
        acc[1] = (f32x4){0.f,0.f,0.f,0.f};
        #pragma unroll
        for (int kc = 0; kc < 16; ++kc) {
            bf16x8 a = *(const bf16x8*)(&xn[l15][kc * 32 + l4 * 8]);
            #pragma unroll
            for (int nf = 0; nf < 2; ++nf) {
                bf16x8 b = *(const bf16x8*)(w1T + (size_t)(w * 32 + nf * 16 + l15) * 512 + kc * 32 + l4 * 8);
                acc[nf] = __builtin_amdgcn_mfma_f32_16x16x32_bf16(a, b, acc[nf], 0, 0, 0);
            }
        }
        #pragma unroll
        for (int nf = 0; nf < 2; ++nf)
            #pragma unroll
            for (int r = 0; r < 4; ++r) {
                int row = l4 * 4 + r;
                int col = w * 32 + nf * 16 + l15;
                float v = fmaxf(acc[nf][r] + b1[col], 0.f);
                v = (v - bn1m[col]) * rsqrtf(bn1v[col] + EPSK) * bn1g[col] + bn1b[col];
                h1s[row][col] = __float2bfloat16(v);
            }
    }
    __syncthreads();

    // stage2 (MFMA): 128 -> 64, relu -> h2s f32
    {
        f32x4 acc = (f32x4){0.f,0.f,0.f,0.f};
        #pragma unroll
        for (int kc = 0; kc < 4; ++kc) {
            bf16x8 a = *(const bf16x8*)(&h1s[l15][kc * 32 + l4 * 8]);
            bf16x8 b = *(const bf16x8*)(w2T + (size_t)(w * 16 + l15) * 128 + kc * 32 + l4 * 8);
            acc = __builtin_amdgcn_mfma_f32_16x16x32_bf16(a, b, acc, 0, 0, 0);
        }
        #pragma unroll
        for (int r = 0; r < 4; ++r) {
            int row = l4 * 4 + r, col = w * 16 + l15;
            h2s[row][col] = fmaxf(acc[r] + b2[col], 0.f);
        }
    }
    __syncthreads();

    const int row = tid >> 4, ci = tid & 15;
    // stage3 (scalar): 64 -> 32, relu
    {
        float a0 = b3[ci * 2], a1 = b3[ci * 2 + 1];
        #pragma unroll 4
        for (int k = 0; k < 64; ++k) {
            float xv = h2s[row][k];
            a0 += xv * w3[k * 32 + ci * 2];
            a1 += xv * w3[k * 32 + ci * 2 + 1];
        }
        h3s[row][ci * 2] = fmaxf(a0, 0.f);
        h3s[row][ci * 2 + 1] = fmaxf(a1, 0.f);
    }
    __syncthreads();
    // stage4 (scalar): 32 -> 16, relu, bn2, write seq_bf
    {
        float a = b4[ci];
        #pragma unroll
        for (int k = 0; k < 32; ++k) a += h3s[row][k] * w4[k * 16 + ci];
        float v = fmaxf(a, 0.f);
        v = (v - bn2m[ci]) * rsqrtf(bn2v[ci] + EPSK) * bn2g[ci] + bn2b[ci];
        int g = g0 + row, bb = g >> 8, tt = g & 255;
        __hip_bfloat16* sr = seqbf + ((size_t)tt * 256 + bb) * 32;
        sr[ci] = __float2bfloat16(v);
        sr[16 + ci] = (ci == 0) ? __float2bfloat16((float)yp[g]) : __float2bfloat16(0.f);
    }
}

// ---------------- persistent bidirectional LSTM (R6 protocol, observation-side tuned) ----------------
// 256 blocks x 256 threads, co-resident by sizing (__launch_bounds__(256,2), LDS 55KB).
// block: g = bid&15 -> dir=g&1, mt=g>>1 (32 batch rows); strip = bid>>4 (32 h-cols).
// Weights register-resident; c in registers. h exchanged through the LLC via sc0/sc1.
// Producer side UNCHANGED from R6/R11 (proven): per-wave vmcnt(0) -> syncthreads ->
// tid0 relaxed agent-scope RMW. Consumer side: wave-parallel spin at loop top (each
// wave's lane 0 spins a relaxed atomic load; exec-mask divergence holds the wave),
// then each wave stages its own quarter immediately. Aenc nt store deferred past
// the signal (off the critical path).

__global__ void __launch_bounds__(256, 2)
lstm_persistent(const __hip_bfloat16* __restrict__ BTcat,   // [dir][2048][544]
                const float* __restrict__ biasz,            // [dir][2048]
                const __hip_bfloat16* __restrict__ seqbf,   // [T][B][32]
                __hip_bfloat16* __restrict__ hbuf,          // [2 parity][2 dir][256][512]
                float* __restrict__ cbuf,                   // [dir][256][512]
                __hip_bfloat16* __restrict__ Aenc,          // [B][T][1024]
                unsigned int* __restrict__ ctrs)            // [16 groups][32]
{
    const int bid = blockIdx.x;
    const int g = bid & 15;
    const int dirv = g & 1;
    const int mt = g >> 1;
    const int strip = bid >> 4;
    const int tid = threadIdx.x;
    const int w = tid >> 6;          // gate index
    const int lane = tid & 63;
    const int l15 = lane & 15, l4 = lane >> 4;

    __shared__ __align__(16) unsigned char Atile[32 * 1152];  // 32 rows x 72 16B-slots
    __shared__ __align__(16) float zbuf[4][32][36];

    // ---- load B-fragments into registers (once) ----
    bf16x8 bw[2][17];
    {
        const __hip_bfloat16* BT = BTcat + (size_t)dirv * 2048 * 544;
        #pragma unroll
        for (int nf = 0; nf < 2; ++nf) {
            const __hip_bfloat16* bp = BT + (size_t)(w * 512 + strip * 32 + nf * 16 + l15) * 544 + l4 * 8;
            #pragma unroll
            for (int kc = 0; kc < 17; ++kc)
                bw[nf][kc] = *(const bf16x8*)(bp + kc * 32);
        }
    }

    // ---- epilogue coords: each thread owns 1 row x 4 adjacent cols ----
    const int rr = tid >> 3;            // 0..31 row within tile
    const int c0 = (tid & 7) * 4;       // col within strip
    const int hcol0 = strip * 32 + c0;
    const int browE = mt * 32 + rr;
    const float* bias = biasz + dirv * 2048;
    const f32x4 b_i = *(const f32x4*)(bias + hcol0);
    const f32x4 b_f = *(const f32x4*)(bias + 512 + hcol0);
    const f32x4 b_g = *(const f32x4*)(bias + 1024 + hcol0);
    const f32x4 b_o = *(const f32x4*)(bias + 1536 + hcol0);

    float creg[4] = {0.f, 0.f, 0.f, 0.f};
    unsigned int* ctr = ctrs + g * 32;
    const int swzA = l15 & 7;

    for (int t = 0; t < 256; ++t) {
        const int tpos = dirv ? (255 - t) : t;

        // ---- wave-parallel wait for h(t): lane 0 spins, divergence holds the wave ----
        if (t > 0) {
            if (lane == 0) {
                const unsigned target = 16u * (unsigned)t;
                while (__hip_atomic_load(ctr, __ATOMIC_RELAXED, __HIP_MEMORY_SCOPE_AGENT) < target)
                    __builtin_amdgcn_s_sleep(1);
            }
        }

        // ---- stage h tile [32][512] (LLC loads) + seq [32][32] into swizzled LDS ----
        {
            const unsigned char* hsrc = (const unsigned char*)
                (hbuf + ((size_t)(t & 1) * 2 + dirv) * 131072 + (size_t)mt * 32 * 512);
            f32x4 hv[8];
            #pragma unroll
            for (int it = 0; it < 8; ++it)
                hv[it] = load16_coh(hsrc + (it * 256 + tid) * 16);
            f32x4 sv;
            if (tid < 128) {
                const __hip_bfloat16* sp = seqbf + ((size_t)tpos * 256 + mt * 32 + (tid >> 2)) * 32 + (tid & 3) * 8;
                sv = *(const f32x4*)sp;
            }
            asm volatile("s_waitcnt vmcnt(0)" ::: "memory");
            #pragma unroll
            for (int it = 0; it < 8; ++it) {
                int c = it * 256 + tid;
                int row = c >> 6, s = c & 63;
                *(f32x4*)(Atile + row * 1152 + ((s ^ (row & 7)) << 4)) = hv[it];
            }
            if (tid < 128) {
                int row = tid >> 2, s = 64 + (tid & 3);
                *(f32x4*)(Atile + row * 1152 + ((s ^ (row & 7)) << 4)) = sv;
            }
        }
        __syncthreads();

        // ---- MFMA: z[32 rows][32 cols] for gate w ----
        f32x4 acc[2][2];
        acc[0][0] = (f32x4){0.f,0.f,0.f,0.f}; acc[0][1] = (f32x4){0.f,0.f,0.f,0.f};
        acc[1][0] = (f32x4){0.f,0.f,0.f,0.f}; acc[1][1] = (f32x4){0.f,0.f,0.f,0.f};
        #pragma unroll
        for (int kc = 0; kc < 17; ++kc) {
            int swz = ((kc * 4 + l4) ^ swzA) << 4;
            bf16x8 a0 = *(const bf16x8*)(Atile + l15 * 1152 + swz);
            bf16x8 a1 = *(const bf16x8*)(Atile + (16 + l15) * 1152 + swz);
            acc[0][0] = __builtin_amdgcn_mfma_f32_16x16x32_bf16(a0, bw[0][kc], acc[0][0], 0, 0, 0);
            acc[0][1] = __builtin_amdgcn_mfma_f32_16x16x32_bf16(a0, bw[1][kc], acc[0][1], 0, 0, 0);
            acc[1][0] = __builtin_amdgcn_mfma_f32_16x16x32_bf16(a1, bw[0][kc], acc[1][0], 0, 0, 0);
            acc[1][1] = __builtin_amdgcn_mfma_f32_16x16x32_bf16(a1, bw[1][kc], acc[1][1], 0, 0, 0);
        }

        // ---- gate exchange: z -> LDS (C/D: col=lane&15, row=(lane>>4)*4+reg) ----
        #pragma unroll
        for (int mf = 0; mf < 2; ++mf)
            #pragma unroll
            for (int nf = 0; nf < 2; ++nf)
                #pragma unroll
                for (int r = 0; r < 4; ++r)
                    zbuf[w][mf * 16 + l4 * 4 + r][nf * 16 + l15] = acc[mf][nf][r];
        __syncthreads();

        // ---- epilogue: 1 row x 4 cols per thread; h store now, Aenc deferred ----
        u32x2 hp;
        {
            f32x4 zi4 = *(const f32x4*)(&zbuf[0][rr][c0]);
            f32x4 zf4 = *(const f32x4*)(&zbuf[1][rr][c0]);
            f32x4 zg4 = *(const f32x4*)(&zbuf[2][rr][c0]);
            f32x4 zo4 = *(const f32x4*)(&zbuf[3][rr][c0]);
            unsigned short hb[4];
            #pragma unroll
            for (int j = 0; j < 4; ++j) {
                float iv = sigm(zi4[j] + b_i[j]);
                float fv = sigm(zf4[j] + b_f[j]);
                float gv = ftanh(zg4[j] + b_g[j]);
                float ov = sigm(zo4[j] + b_o[j]);
                float cnew = fv * creg[j] + iv * gv;
                creg[j] = cnew;
                hb[j] = f2bfu(ov * ftanh(cnew));
            }
            hp[0] = (unsigned)hb[0] | ((unsigned)hb[1] << 16);
            hp[1] = (unsigned)hb[2] | ((unsigned)hb[3] << 16);
            __hip_bfloat16* hdst = hbuf + ((size_t)((t + 1) & 1) * 2 + dirv) * 131072;
            store8_coh(hdst + (size_t)browE * 512 + hcol0, hp);
        }

        // ---- signal: h acked at LLC by all waves, then tid0 RMW (R6-proven) ----
        if (t < 255) {
            asm volatile("s_waitcnt vmcnt(0)" ::: "memory");   // h stores acked (per wave)
            __syncthreads();                                   // all waves acked
            if (tid == 0)
                __hip_atomic_fetch_add(ctr, 1u, __ATOMIC_RELAXED, __HIP_MEMORY_SCOPE_AGENT);
        }
        // ---- deferred Aenc store (overlaps next spin; never read by this kernel) ----
        store8_nt(reinterpret_cast<short*>(Aenc) + ((size_t)browE * 256 + tpos) * 1024 + dirv * 512 + hcol0, hp);
    }

    // ---- write out final c ----
    *(f32x4*)(cbuf + (size_t)dirv * 131072 + (size_t)browE * 512 + hcol0) =
        (f32x4){creg[0], creg[1], creg[2], creg[3]};
}

// ---------------- decoder cell (single step, KD=1024) ----------------

template<int MT, int KD>
__global__ __launch_bounds__(256)
void dec_cell_kernel(const __hip_bfloat16* __restrict__ Abase,
                     const __hip_bfloat16* __restrict__ BTbase,
                     const float* __restrict__ bias,
                     const float* __restrict__ Cin,
                     float* __restrict__ HdecOut)
{
    constexpr int RB = KD * 2;
    constexpr int MF = MT / 16;
    constexpr int KSTEPS = KD / 32;
    const int strip = blockIdx.x;
    const int mt = blockIdx.y;
    const int tid = threadIdx.x;
    const int w = tid >> 6;
    const int lane = tid & 63;

    __shared__ __align__(16) unsigned char Als[MT * KD * 2];
    __shared__ float zbuf[4][MT][33];

    const __hip_bfloat16* A = Abase + (size_t)(mt * MT) * KD;
    const __hip_bfloat16* BT = BTbase;

    const unsigned char* Ac = (const unsigned char*)A;
    #pragma unroll
    for (int it = 0; it < (MT * KD * 2) / 4096; ++it) {
        int p = it * 4096 + tid * 16;
        int row = p / RB;
        int slot = (p % RB) >> 4;
        int ls = slot ^ (row & 7);
        *(f32x4*)(Als + row * RB + ls * 16) = *(const f32x4*)(Ac + p);
    }
    __syncthreads();

    f32x4 acc[MF][2];
    #pragma unroll
    for (int mf = 0; mf < MF; ++mf)
        #pragma unroll
        for (int nf = 0; nf < 2; ++nf)
            acc[mf][nf] = (f32x4){0.f,0.f,0.f,0.f};

    const int l15 = lane & 15, l4 = lane >> 4;
    #pragma unroll 4
    for (int kc = 0; kc < KSTEPS; ++kc) {
        bf16x8 a[MF], bb[2];
        int kslot = kc * 4 + l4;
        #pragma unroll
        for (int mf = 0; mf < MF; ++mf) {
            int row = mf * 16 + l15;
            a[mf] = *(const bf16x8*)(Als + row * RB + ((kslot ^ (row & 7)) << 4));
        }
        #pragma unroll
        for (int nf = 0; nf < 2; ++nf) {
            int zr = w * 512 + strip * 32 + nf * 16 + l15;
            bb[nf] = *(const bf16x8*)(BT + (size_t)zr * KD + kc * 32 + l4 * 8);
        }
        #pragma unroll
        for (int mf = 0; mf < MF; ++mf)
            #pragma unroll
            for (int nf = 0; nf < 2; ++nf)
                acc[mf][nf] = __builtin_amdgcn_mfma_f32_16x16x32_bf16(a[mf], bb[nf], acc[mf][nf], 0, 0, 0);
    }

    #pragma unroll
    for (int mf = 0; mf < MF; ++mf)
        #pragma unroll
        for (int nf = 0; nf < 2; ++nf)
            #pragma unroll
            for (int r = 0; r < 4; ++r)
                zbuf[w][mf * 16 + l4 * 4 + r][nf * 16 + l15] = acc[mf][nf][r];
    __syncthreads();

    constexpr int NE = MT * 32 / 256;
    #pragma unroll
    for (int e = 0; e < NE; ++e) {
        int idx = e * 256 + tid;
        int r = idx >> 5, col = idx & 31;
        int hcol = strip * 32 + col;
        int brow = mt * MT + r;
        float zi = zbuf[0][r][col] + bias[hcol];
        float zf = zbuf[1][r][col] + bias[512 + hcol];
        float zg = zbuf[2][r][col] + bias[1024 + hcol];
        float zo = zbuf[3][r][col] + bias[1536 + hcol];
        float iv = sigm(zi), fv = sigm(zf), gv = ftanh(zg);
        float cold = Cin[(size_t)brow * 512 + hcol];
        float cnew = fv * cold + iv * gv;
        HdecOut[(size_t)brow * 512 + hcol] = sigm(zo) * ftanh(cnew);
    }
}

// ---------------- generic small GEMM: outF[M][N] = A[M][K](bf16) @ BT[N][K]^T + bias ----------------

__global__ __launch_bounds__(256)
void gemm_kernel(const __hip_bfloat16* __restrict__ A,
                 const __hip_bfloat16* __restrict__ BT,
                 const float* __restrict__ bias,
                 float* __restrict__ outF,
                 int M, int N, int K)
{
    const int tid = threadIdx.x;
    const int wv = tid >> 6, lane = tid & 63;
    const int wr = wv >> 1, wc = wv & 1;
    const int m0 = blockIdx.y * 64, n0 = blockIdx.x * 64;
    const int l15 = lane & 15, l4 = lane >> 4;
    f32x4 acc[2][2];
    #pragma unroll
    for (int i = 0; i < 2; ++i)
        #pragma unroll
        for (int j = 0; j < 2; ++j) acc[i][j] = (f32x4){0.f,0.f,0.f,0.f};
    for (int kc = 0; kc < K / 32; ++kc) {
        bf16x8 a[2], b[2];
        #pragma unroll
        for (int m2 = 0; m2 < 2; ++m2)
            a[m2] = *(const bf16x8*)(A + (size_t)(m0 + wr * 32 + m2 * 16 + l15) * K + kc * 32 + l4 * 8);
        #pragma unroll
        for (int n2 = 0; n2 < 2; ++n2)
            b[n2] = *(const bf16x8*)(BT + (size_t)(n0 + wc * 32 + n2 * 16 + l15) * K + kc * 32 + l4 * 8);
        #pragma unroll
        for (int m2 = 0; m2 < 2; ++m2)
            #pragma unroll
            for (int n2 = 0; n2 < 2; ++n2)
                acc[m2][n2] = __builtin_amdgcn_mfma_f32_16x16x32_bf16(a[m2], b[n2], acc[m2][n2], 0, 0, 0);
    }
    #pragma unroll
    for (int m2 = 0; m2 < 2; ++m2)
        #pragma unroll
        for (int n2 = 0; n2 < 2; ++n2)
            #pragma unroll
            for (int r = 0; r < 4; ++r) {
                int row = m0 + wr * 32 + m2 * 16 + l4 * 4 + r;
                int col = n0 + wc * 32 + n2 * 16 + l15;
                float v = acc[m2][n2][r];
                if (bias) v += bias[col];
                outF[(size_t)row * N + col] = v;
            }
}

// ---------------- attention ----------------

__global__ __launch_bounds__(256)
void attn_kernel(const __hip_bfloat16* __restrict__ Aenc,
                 const float* __restrict__ qh,
                 __hip_bfloat16* __restrict__ Aactx)
{
    const int b = blockIdx.x, tid = threadIdx.x;
    __shared__ float qs[1024];
    __shared__ float sc[256];
    __shared__ float wred[4];
    for (int i = tid; i < 1024; i += 256) qs[i] = qh[(size_t)b * 1024 + i];
    __syncthreads();
    const __hip_bfloat16* ar = Aenc + ((size_t)b * 256 + tid) * 1024;
    float s = 0.f;
    for (int j8 = 0; j8 < 128; ++j8) {
        bf16x8 v = *(const bf16x8*)(ar + j8 * 8);
        #pragma unroll
        for (int e = 0; e < 8; ++e) s += bf2f(v[e]) * qs[j8 * 8 + e];
    }
    float m = s;
    for (int o = 32; o; o >>= 1) m = fmaxf(m, __shfl_xor(m, o));
    if ((tid & 63) == 0) wred[tid >> 6] = m;
    __syncthreads();
    m = fmaxf(fmaxf(wred[0], wred[1]), fmaxf(wred[2], wred[3]));
    __syncthreads();
    float ev = __expf(s - m);
    float ss = ev;
    for (int o = 32; o; o >>= 1) ss += __shfl_xor(ss, o);
    if ((tid & 63) == 0) wred[tid >> 6] = ss;
    __syncthreads();
    float tot = wred[0] + wred[1] + wred[2] + wred[3];
    sc[tid] = ev / tot;
    __syncthreads();
    float a0 = 0, a1 = 0, a2 = 0, a3 = 0;
    for (int t2 = 0; t2 < 256; ++t2) {
        float p = sc[t2];
        s16x4 v = *(const s16x4*)(Aenc + ((size_t)b * 256 + t2) * 1024 + tid * 4);
        a0 += p * bf2f(v[0]); a1 += p * bf2f(v[1]); a2 += p * bf2f(v[2]); a3 += p * bf2f(v[3]);
    }
    __hip_bfloat16* dst = Aactx + (size_t)b * 1024 + tid * 4;
    dst[0] = __float2bfloat16(a0); dst[1] = __float2bfloat16(a1);
    dst[2] = __float2bfloat16(a2); dst[3] = __float2bfloat16(a3);
}

// ---------------- small pack kernels ----------------

__global__ void pack_state_kernel(const __hip_bfloat16* __restrict__ hbuf0,
                                  const float* __restrict__ cbuf,
                                  __hip_bfloat16* __restrict__ Astate,
                                  __hip_bfloat16* __restrict__ Astatec)
{
    int i = blockIdx.x * blockDim.x + threadIdx.x;
    if (i < 262144) {
        int bb = i >> 10, jj = i & 1023;
        int dir = jj >> 9, j = jj & 511;
        size_t src = (size_t)dir * 131072 + bb * 512 + j;
        Astate[i] = hbuf0[src];
        Astatec[i] = __float2bfloat16(cbuf[src]);
    }
}

__global__ void pack_dec_kernel(const float* __restrict__ attnf,
                                const float* __restrict__ sh,
                                __hip_bfloat16* __restrict__ Adec)
{
    int i = blockIdx.x * blockDim.x + threadIdx.x;
    if (i < 262144) {
        int bb = i >> 10, jj = i & 1023;
        float v = (jj < 512) ? attnf[bb * 512 + jj] : sh[bb * 512 + (jj - 512)];
        Adec[i] = __float2bfloat16(v);
    }
}

__global__ void out_kernel(const float* __restrict__ hdec,
                           const float* __restrict__ out_w,
                           const float* __restrict__ out_b,
                           float* __restrict__ out)
{
    int b = blockIdx.x, lane = threadIdx.x;
    float a0 = 0.f, a1 = 0.f;
    for (int h = lane; h < 512; h += 64) {
        float hv = hdec[(size_t)b * 512 + h];
        a0 += hv * out_w[2 * h];
        a1 += hv * out_w[2 * h + 1];
    }
    for (int o = 32; o; o >>= 1) { a0 += __shfl_down(a0, o); a1 += __shfl_down(a1, o); }
    if (lane == 0) { out[2 * b] = a0 + out_b[0]; out[2 * b + 1] = a1 + out_b[1]; }
}

// ---------------- launch ----------------

extern "C" void kernel_launch(void* const* d_in, const int* in_sizes, int n_in,
                              void* d_out, int out_size, void* d_ws, size_t ws_size,
                              hipStream_t stream) {
    (void)in_sizes; (void)n_in; (void)out_size; (void)ws_size;
    const float* x        = (const float*)d_in[0];
    const int*   y_past   = (const int*)d_in[1];
    const float* ln_g     = (const float*)d_in[2];
    const float* ln_b     = (const float*)d_in[3];
    const float* w1       = (const float*)d_in[4];
    const float* b1       = (const float*)d_in[5];
    const float* w2       = (const float*)d_in[6];
    const float* b2       = (const float*)d_in[7];
    const float* w3       = (const float*)d_in[8];
    const float* b3       = (const float*)d_in[9];
    const float* w4       = (const float*)d_in[10];
    const float* b4       = (const float*)d_in[11];
    const float* bn1_g    = (const float*)d_in[12];
    const float* bn1_b    = (const float*)d_in[13];
    const float* bn1_m    = (const float*)d_in[14];
    const float* bn1_v    = (const float*)d_in[15];
    const float* bn2_g    = (const float*)d_in[16];
    const float* bn2_b    = (const float*)d_in[17];
    const float* bn2_m    = (const float*)d_in[18];
    const float* bn2_v    = (const float*)d_in[19];
    const float* efwx     = (const float*)d_in[20];
    const float* efwh     = (const float*)d_in[21];
    const float* efbias   = (const float*)d_in[22];
    const float* ebwx     = (const float*)d_in[23];
    const float* ebwh     = (const float*)d_in[24];
    const float* ebbias   = (const float*)d_in[25];
    const float* dec_wx   = (const float*)d_in[26];
    const float* dec_wh   = (const float*)d_in[27];
    const float* dec_bias = (const float*)d_in[28];
    const float* proj_w   = (const float*)d_in[29];
    const float* proj_b   = (const float*)d_in[30];
    const float* sph_w    = (const float*)d_in[31];
    const float* sph_b    = (const float*)d_in[32];
    const float* spc_w    = (const float*)d_in[33];
    const float* spc_b    = (const float*)d_in[34];
    const float* out_w    = (const float*)d_in[35];
    const float* out_b    = (const float*)d_in[36];

    char* wsb = (char*)d_ws;
    size_t off = 0;
    auto alloc = [&](size_t bytes) -> char* {
        char* r = wsb + off;
        off = (off + bytes + 255) & ~(size_t)255;
        return r;
    };
    __hip_bfloat16* BTcat   = (__hip_bfloat16*)alloc(2ull * 2048 * 544 * 2);   // [dir][2048][544]
    __hip_bfloat16* decT    = (__hip_bfloat16*)alloc(2048ull * 1024 * 2);      // [2048][1024]
    __hip_bfloat16* projT   = (__hip_bfloat16*)alloc(512ull * 1024 * 2);       // [512][1024]
    __hip_bfloat16* projWb  = (__hip_bfloat16*)alloc(1024ull * 512 * 2);       // [1024][512]
    __hip_bfloat16* sphT    = (__hip_bfloat16*)alloc(512ull * 1024 * 2);
    __hip_bfloat16* spcT    = (__hip_bfloat16*)alloc(512ull * 1024 * 2);
    __hip_bfloat16* w1T     = (__hip_bfloat16*)alloc(128ull * 512 * 2);        // [128][512]
    __hip_bfloat16* w2T     = (__hip_bfloat16*)alloc(64ull * 128 * 2);         // [64][128]
    float*          biasz   = (float*)alloc(2ull * 2048 * 4);
    __hip_bfloat16* seqbf   = (__hip_bfloat16*)alloc(256ull * 256 * 32 * 2);   // [T][B][32]
    __hip_bfloat16* hbuf    = (__hip_bfloat16*)alloc(2ull * 2 * 256 * 512 * 2);// [par][dir][B][H]
    float*          cbuf    = (float*)alloc(2ull * 256 * 512 * 4);             // [dir][B][H]
    __hip_bfloat16* Aenc    = (__hip_bfloat16*)alloc(65536ull * 1024 * 2);     // [B*T][2H]
    unsigned int*   ctrs    = (unsigned int*)alloc(16ull * 32 * 4);            // group barrier counters
    __hip_bfloat16* Astate  = (__hip_bfloat16*)alloc(256ull * 1024 * 2);
    __hip_bfloat16* Astatec = (__hip_bfloat16*)alloc(256ull * 1024 * 2);
    float*          state_h = (float*)alloc(256ull * 512 * 4);
    float*          state_c = (float*)alloc(256ull * 512 * 4);
    __hip_bfloat16* Ash     = (__hip_bfloat16*)alloc(256ull * 512 * 2);
    float*          qh      = (float*)alloc(256ull * 1024 * 4);
    __hip_bfloat16* Aactx   = (__hip_bfloat16*)alloc(256ull * 1024 * 2);
    float*          attnf   = (float*)alloc(256ull * 512 * 4);
    __hip_bfloat16* Adec    = (__hip_bfloat16*)alloc(256ull * 1024 * 2);
    float*          hdec    = (float*)alloc(256ull * 512 * 4);

    // ---- weight prep: one batched tiled-transpose launch ----
    (void)hipMemsetAsync(BTcat, 0, 2ull * 2048 * 544 * 2, stream);   // zero K-pad cols
    {
        TransJobs jobs;
        jobs.src[0]  = efwh;   jobs.dst[0]  = BTcat;              jobs.K[0]  = 512;  jobs.N[0]  = 2048; jobs.kOff[0]  = 0;   jobs.KD[0]  = 544;
        jobs.src[1]  = efwx;   jobs.dst[1]  = BTcat;              jobs.K[1]  = 17;   jobs.N[1]  = 2048; jobs.kOff[1]  = 512; jobs.KD[1]  = 544;
        jobs.src[2]  = ebwh;   jobs.dst[2]  = BTcat + 2048 * 544; jobs.K[2]  = 512;  jobs.N[2]  = 2048; jobs.kOff[2]  = 0;   jobs.KD[2]  = 544;
        jobs.src[3]  = ebwx;   jobs.dst[3]  = BTcat + 2048 * 544; jobs.K[3]  = 17;   jobs.N[3]  = 2048; jobs.kOff[3]  = 512; jobs.KD[3]  = 544;
        jobs.src[4]  = proj_w; jobs.dst[4]  = projT;              jobs.K[4]  = 1024; jobs.N[4]  = 512;  jobs.kOff[4]  = 0;   jobs.KD[4]  = 1024;
        jobs.src[5]  = sph_w;  jobs.dst[5]  = sphT;               jobs.K[5]  = 1024; jobs.N[5]  = 512;  jobs.kOff[5]  = 0;   jobs.KD[5]  = 1024;
        jobs.src[6]  = spc_w;  jobs.dst[6]  = spcT;               jobs.K[6]  = 1024; jobs.N[6]  = 512;  jobs.kOff[6]  = 0;   jobs.KD[6]  = 1024;
        jobs.src[7]  = dec_wx; jobs.dst[7]  = decT;               jobs.K[7]  = 512;  jobs.N[7]  = 2048; jobs.kOff[7]  = 0;   jobs.KD[7]  = 1024;
        jobs.src[8]  = dec_wh; jobs.dst[8]  = decT;               jobs.K[8]  = 512;  jobs.N[8]  = 2048; jobs.kOff[8]  = 512; jobs.KD[8]  = 1024;
        jobs.src[9]  = w1;     jobs.dst[9]  = w1T;                jobs.K[9]  = 512;  jobs.N[9]  = 128;  jobs.kOff[9]  = 0;   jobs.KD[9]  = 512;
        jobs.src[10] = w2;     jobs.dst[10] = w2T;                jobs.K[10] = 128;  jobs.N[10] = 64;   jobs.kOff[10] = 0;   jobs.KD[10] = 128;
        trans_tiled_kernel<<<dim3(1024, NTJOBS), 256, 0, stream>>>(jobs);
    }
    cvt_f2b_kernel<<<1024, 256, 0, stream>>>(projWb, proj_w, 1024 * 512);
    copy_f_kernel<<<8, 256, 0, stream>>>(biasz, efbias, 2048);
    copy_f_kernel<<<8, 256, 0, stream>>>(biasz + 2048, ebbias, 2048);

    (void)hipMemsetAsync(hbuf, 0, 2ull * 256 * 512 * 2, stream);      // parity-0 h = 0
    (void)hipMemsetAsync(ctrs, 0, 16ull * 32 * 4, stream);            // barrier counters = 0

    // ---- funnel ----
    funnel_kernel<<<4096, 256, 0, stream>>>(x, y_past, ln_g, ln_b,
        w1T, b1, w2T, b2, w3, b3, w4, b4,
        bn1_g, bn1_b, bn1_m, bn1_v, bn2_g, bn2_b, bn2_m, bn2_v, seqbf);

    // ---- persistent bidirectional LSTM (single plain dispatch; co-resident by sizing) ----
    lstm_persistent<<<dim3(256), dim3(256), 0, stream>>>(
        BTcat, biasz, seqbf, hbuf, cbuf, Aenc, ctrs);

    // ---- states ----
    pack_state_kernel<<<1024, 256, 0, stream>>>(hbuf, cbuf, Astate, Astatec);
    gemm_kernel<<<dim3(8, 4), 256, 0, stream>>>(Astate, sphT, sph_b, state_h, 256, 512, 1024);
    gemm_kernel<<<dim3(8, 4), 256, 0, stream>>>(Astatec, spcT, spc_b, state_c, 256, 512, 1024);
    cvt_f2b_kernel<<<512, 256, 0, stream>>>(Ash, state_h, 256 * 512);

    // ---- attention (proj folded out): qh = state_h @ proj_w^T ----
    gemm_kernel<<<dim3(16, 4), 256, 0, stream>>>(Ash, projWb, nullptr, qh, 256, 1024, 512);
    attn_kernel<<<256, 256, 0, stream>>>(Aenc, qh, Aactx);
    gemm_kernel<<<dim3(8, 4), 256, 0, stream>>>(Aactx, projT, proj_b, attnf, 256, 512, 1024);

    // ---- decoder cell ----
    pack_dec_kernel<<<1024, 256, 0, stream>>>(attnf, state_h, Adec);
    dec_cell_kernel<32, 1024><<<dim3(16, 8), 256, 0, stream>>>(
        Adec, decT, dec_bias, state_c, hdec);

    // ---- output ----
    out_kernel<<<256, 64, 0, stream>>>(hdec, out_w, out_b, (float*)d_out);
}

// Round 13
// 1089.401 us; speedup vs baseline: 1.0330x; 1.0330x over previous
//
#include <hip/hip_runtime.h>
#include <hip/hip_bf16.h>

// Model dims: B=256, T=256, F=512, H=512, DIN=17 (padded to 32 in seq concat)
#define EPSK 1e-3f

using bf16x8 = __attribute__((ext_vector_type(8))) short;
using s16x4  = __attribute__((ext_vector_type(4))) short;
using f32x4  = __attribute__((ext_vector_type(4))) float;
using f32x2  = __attribute__((ext_vector_type(2))) float;
using u32x2  = __attribute__((ext_vector_type(2))) unsigned int;

__device__ __forceinline__ float bf2f(short s) {
    union { unsigned u; float f; } x; x.u = ((unsigned)(unsigned short)s) << 16; return x.f;
}
__device__ __forceinline__ unsigned short f2bfu(float f) {
    union { float f; unsigned u; } x; x.f = f;
    unsigned r = x.u + 0x7fffu + ((x.u >> 16) & 1u);   // RNE
    return (unsigned short)(r >> 16);
}
__device__ __forceinline__ float sigm(float x) { return 1.0f / (1.0f + __expf(-x)); }
__device__ __forceinline__ float ftanh(float x) {
    float e = __expf(2.0f * x);
    return 1.0f - 2.0f / (e + 1.0f);
}

// device-coherent (LLC) ops — bypass XCD-local caches (R6-proven)
__device__ __forceinline__ f32x4 load16_coh(const void* p) {
    f32x4 v;
    asm volatile("global_load_dwordx4 %0, %1, off sc0 sc1" : "=v"(v) : "v"(p) : "memory");
    return v;
}
__device__ __forceinline__ void store4_coh(void* p, unsigned v) {
    asm volatile("global_store_dword %0, %1, off sc0 sc1" :: "v"(p), "v"(v) : "memory");
}
__device__ __forceinline__ void store4_nt(void* p, unsigned v) {
    asm volatile("global_store_dword %0, %1, off nt" :: "v"(p), "v"(v) : "memory");
}

// ---------------- utility kernels ----------------

__global__ void cvt_f2b_kernel(__hip_bfloat16* __restrict__ dst, const float* __restrict__ src, int n)
{
    for (int i = blockIdx.x * blockDim.x + threadIdx.x; i < n; i += gridDim.x * blockDim.x)
        dst[i] = __float2bfloat16(src[i]);
}

__global__ void copy_f_kernel(float* __restrict__ dst, const float* __restrict__ src, int n)
{
    for (int i = blockIdx.x * blockDim.x + threadIdx.x; i < n; i += gridDim.x * blockDim.x)
        dst[i] = src[i];
}

// batched tiled transpose: dst[n][kOff+k](bf16, stride KD) = src[k][n] (f32 [K][N])
#define NTJOBS 11
struct TransJobs {
    const float* src[NTJOBS];
    __hip_bfloat16* dst[NTJOBS];
    int K[NTJOBS], N[NTJOBS], kOff[NTJOBS], KD[NTJOBS];
};

__global__ __launch_bounds__(256)
void trans_tiled_kernel(TransJobs jobs)
{
    const int j = blockIdx.y;
    const int K = jobs.K[j], N = jobs.N[j];
    const int tilesN = (N + 31) >> 5;
    const int tilesK = (K + 31) >> 5;
    if ((int)blockIdx.x >= tilesN * tilesK) return;
    const int tk = blockIdx.x / tilesN, tn = blockIdx.x % tilesN;
    const int kOff = jobs.kOff[j], KD = jobs.KD[j];
    const float* src = jobs.src[j];
    __hip_bfloat16* dst = jobs.dst[j];
    __shared__ float tile[32][33];
    const int tid = threadIdx.x;
    #pragma unroll
    for (int i = 0; i < 4; ++i) {
        int e = i * 256 + tid;
        int r = e >> 5, c = e & 31;
        int k = tk * 32 + r, n = tn * 32 + c;
        tile[r][c] = (k < K && n < N) ? src[(size_t)k * N + n] : 0.f;
    }
    __syncthreads();
    #pragma unroll
    for (int i = 0; i < 4; ++i) {
        int e = i * 256 + tid;
        int rn = e >> 5, ck = e & 31;
        int n = tn * 32 + rn, k = tk * 32 + ck;
        if (k < K && n < N) dst[(size_t)n * KD + kOff + k] = __float2bfloat16(tile[ck][rn]);
    }
}

// ---------------- funnel: LN + MLP(MFMA stages 1-2) + BN -> seq_bf [T][B][32] ----------------

__global__ __launch_bounds__(256)
void funnel_kernel(const float* __restrict__ x, const int* __restrict__ yp,
                   const float* __restrict__ ln_g, const float* __restrict__ ln_b,
                   const __hip_bfloat16* __restrict__ w1T,  // [128][512] bf16
                   const float* __restrict__ b1,
                   const __hip_bfloat16* __restrict__ w2T,  // [64][128] bf16
                   const float* __restrict__ b2,
                   const float* __restrict__ w3, const float* __restrict__ b3,
                   const float* __restrict__ w4, const float* __restrict__ b4,
                   const float* __restrict__ bn1g, const float* __restrict__ bn1b,
                   const float* __restrict__ bn1m, const float* __restrict__ bn1v,
                   const float* __restrict__ bn2g, const float* __restrict__ bn2b,
                   const float* __restrict__ bn2m, const float* __restrict__ bn2v,
                   __hip_bfloat16* __restrict__ seqbf)
{
    __shared__ __align__(16) __hip_bfloat16 xn[16][520];   // 1040B row = 65x16B
    __shared__ __align__(16) __hip_bfloat16 h1s[16][136];  // 272B row = 17x16B
    __shared__ float h2s[16][64];
    __shared__ float h3s[16][32];
    const int tid = threadIdx.x;
    const int w = tid >> 6, lane = tid & 63;
    const int l15 = lane & 15, l4 = lane >> 4;
    const int g0 = blockIdx.x * 16;

    for (int pp = 0; pp < 4; ++pp) {
        int r = pp * 4 + w;
        const float* xr = x + (size_t)(g0 + r) * 512;
        f32x4 v0 = *(const f32x4*)(xr + lane * 8);
        f32x4 v1 = *(const f32x4*)(xr + lane * 8 + 4);
        float s = v0[0]+v0[1]+v0[2]+v0[3] + v1[0]+v1[1]+v1[2]+v1[3];
        float q = v0[0]*v0[0]+v0[1]*v0[1]+v0[2]*v0[2]+v0[3]*v0[3]
                + v1[0]*v1[0]+v1[1]*v1[1]+v1[2]*v1[2]+v1[3]*v1[3];
        for (int o = 32; o; o >>= 1) { s += __shfl_xor(s, o); q += __shfl_xor(q, o); }
        float mu = s * (1.0f / 512.0f);
        float var = q * (1.0f / 512.0f) - mu * mu;
        float rs = rsqrtf(var + EPSK);
        union { unsigned short s[8]; f32x4 v; } pk;
        #pragma unroll
        for (int j = 0; j < 8; ++j) {
            int c = lane * 8 + j;
            float xv = (j < 4) ? v0[j] : v1[j - 4];
            pk.s[j] = f2bfu((xv - mu) * rs * ln_g[c] + ln_b[c]);
        }
        *(f32x4*)(&xn[r][lane * 8]) = pk.v;
    }
    __syncthreads();

    // stage1 (MFMA): 512 -> 128, relu, bn1 -> h1s bf16
    {
        f32x4 acc[2];
        acc[0] = (f32x4){0.f,0.f,0.f,0.f};
        acc[1] = (f32x4){0.f,0.f,0.f,0.f};
        #pragma unroll
        for (int kc = 0; kc < 16; ++kc) {
            bf16x8 a = *(const bf16x8*)(&xn[l15][kc * 32 + l4 * 8]);
            #pragma unroll
            for (int nf = 0; nf < 2; ++nf) {
                bf16x8 b = *(const bf16x8*)(w1T + (size_t)(w * 32 + nf * 16 + l15) * 512 + kc * 32 + l4 * 8);
                acc[nf] = __builtin_amdgcn_mfma_f32_16x16x32_bf16(a, b, acc[nf], 0, 0, 0);
            }
        }
        #pragma unroll
        for (int nf = 0; nf < 2; ++nf)
            #pragma unroll
            for (int r = 0; r < 4; ++r) {
                int row = l4 * 4 + r;
                int col = w * 32 + nf * 16 + l15;
                float v = fmaxf(acc[nf][r] + b1[col], 0.f);
                v = (v - bn1m[col]) * rsqrtf(bn1v[col] + EPSK) * bn1g[col] + bn1b[col];
                h1s[row][col] = __float2bfloat16(v);
            }
    }
    __syncthreads();

    // stage2 (MFMA): 128 -> 64, relu -> h2s f32
    {
        f32x4 acc = (f32x4){0.f,0.f,0.f,0.f};
        #pragma unroll
        for (int kc = 0; kc < 4; ++kc) {
            bf16x8 a = *(const bf16x8*)(&h1s[l15][kc * 32 + l4 * 8]);
            bf16x8 b = *(const bf16x8*)(w2T + (size_t)(w * 16 + l15) * 128 + kc * 32 + l4 * 8);
            acc = __builtin_amdgcn_mfma_f32_16x16x32_bf16(a, b, acc, 0, 0, 0);
        }
        #pragma unroll
        for (int r = 0; r < 4; ++r) {
            int row = l4 * 4 + r, col = w * 16 + l15;
            h2s[row][col] = fmaxf(acc[r] + b2[col], 0.f);
        }
    }
    __syncthreads();

    const int row = tid >> 4, ci = tid & 15;
    // stage3 (scalar): 64 -> 32, relu
    {
        float a0 = b3[ci * 2], a1 = b3[ci * 2 + 1];
        #pragma unroll 4
        for (int k = 0; k < 64; ++k) {
            float xv = h2s[row][k];
            a0 += xv * w3[k * 32 + ci * 2];
            a1 += xv * w3[k * 32 + ci * 2 + 1];
        }
        h3s[row][ci * 2] = fmaxf(a0, 0.f);
        h3s[row][ci * 2 + 1] = fmaxf(a1, 0.f);
    }
    __syncthreads();
    // stage4 (scalar): 32 -> 16, relu, bn2, write seq_bf
    {
        float a = b4[ci];
        #pragma unroll
        for (int k = 0; k < 32; ++k) a += h3s[row][k] * w4[k * 16 + ci];
        float v = fmaxf(a, 0.f);
        v = (v - bn2m[ci]) * rsqrtf(bn2v[ci] + EPSK) * bn2g[ci] + bn2b[ci];
        int g = g0 + row, bb = g >> 8, tt = g & 255;
        __hip_bfloat16* sr = seqbf + ((size_t)tt * 256 + bb) * 32;
        sr[ci] = __float2bfloat16(v);
        sr[16 + ci] = (ci == 0) ? __float2bfloat16((float)yp[g]) : __float2bfloat16(0.f);
    }
}

// ---------------- persistent bidirectional LSTM: 512 blocks, 2/CU, R6 protocol ----------------
// M=16 rows/block. bid: g = bid>>4 (0..31 -> dir=g&1, mt16=g>>1), strip = bid&15 (32 cols).
// Co-resident blocks b and b+256 belong to groups g and g+16 (independent chains):
// while one spins on its group barrier, the other computes (block-level TLP).
// Per-block exchange protocol byte-equivalent to R6/R11 (proven): sc0sc1 LLC h
// exchange; vmcnt(0) -> syncthreads -> tid0 relaxed agent RMW + spin -> syncthreads.
// All 512 blocks resident by sizing: __launch_bounds__(256,2), LDS 27.6KB.

__global__ void __launch_bounds__(256, 2)
lstm_persistent(const __hip_bfloat16* __restrict__ BTcat,   // [dir][2048][544]
                const float* __restrict__ biasz,            // [dir][2048]
                const __hip_bfloat16* __restrict__ seqbf,   // [T][B][32]
                __hip_bfloat16* __restrict__ hbuf,          // [2 parity][2 dir][256][512]
                float* __restrict__ cbuf,                   // [dir][256][512]
                __hip_bfloat16* __restrict__ Aenc,          // [B][T][1024]
                unsigned int* __restrict__ ctrs)            // [32 groups][32]
{
    const int bid = blockIdx.x;
    const int g = bid >> 4;              // 0..31
    const int dirv = g & 1;
    const int mt16 = g >> 1;             // 0..15, 16 batch rows each
    const int strip = bid & 15;          // 0..15, 32 h-cols each
    const int tid = threadIdx.x;
    const int w = tid >> 6;              // gate index
    const int lane = tid & 63;
    const int l15 = lane & 15, l4 = lane >> 4;

    __shared__ __align__(16) unsigned char Atile[16 * 1152]; // 18432B
    __shared__ __align__(16) float zbuf[4][16][36];          // 9216B

    // ---- load B-fragments into registers (once) ----
    bf16x8 bw[2][17];
    {
        const __hip_bfloat16* BT = BTcat + (size_t)dirv * 2048 * 544;
        #pragma unroll
        for (int nf = 0; nf < 2; ++nf) {
            const __hip_bfloat16* bp = BT + (size_t)(w * 512 + strip * 32 + nf * 16 + l15) * 544 + l4 * 8;
            #pragma unroll
            for (int kc = 0; kc < 17; ++kc)
                bw[nf][kc] = *(const bf16x8*)(bp + kc * 32);
        }
    }

    // ---- epilogue coords: each thread owns 1 row x 2 adjacent cols ----
    const int rr = tid >> 4;             // 0..15 row within tile
    const int c0 = (tid & 15) * 2;       // col within strip
    const int hcol0 = strip * 32 + c0;
    const int browE = mt16 * 16 + rr;
    const float* bias = biasz + dirv * 2048;
    const float bi0 = bias[hcol0],        bi1 = bias[hcol0 + 1];
    const float bf0 = bias[512 + hcol0],  bf1 = bias[512 + hcol0 + 1];
    const float bg0 = bias[1024 + hcol0], bg1 = bias[1024 + hcol0 + 1];
    const float bo0 = bias[1536 + hcol0], bo1 = bias[1536 + hcol0 + 1];

    float creg0 = 0.f, creg1 = 0.f;
    unsigned int* ctr = ctrs + g * 32;
    const int swzA = l15 & 7;

    for (int t = 0; t < 256; ++t) {
        const int tpos = dirv ? (255 - t) : t;

        // ---- stage h tile [16][512] (LLC loads) + seq [16][32] into swizzled LDS ----
        {
            const unsigned char* hsrc = (const unsigned char*)
                (hbuf + ((size_t)(t & 1) * 2 + dirv) * 131072 + (size_t)mt16 * 16 * 512);
            f32x4 hv[4];
            #pragma unroll
            for (int it = 0; it < 4; ++it)
                hv[it] = load16_coh(hsrc + (it * 256 + tid) * 16);
            f32x4 sv;
            if (tid < 64) {
                const __hip_bfloat16* sp = seqbf + ((size_t)tpos * 256 + mt16 * 16 + (tid >> 2)) * 32 + (tid & 3) * 8;
                sv = *(const f32x4*)sp;
            }
            asm volatile("s_waitcnt vmcnt(0)" ::: "memory");
            #pragma unroll
            for (int it = 0; it < 4; ++it) {
                int c = it * 256 + tid;
                int row = c >> 6, s = c & 63;
                *(f32x4*)(Atile + row * 1152 + ((s ^ (row & 7)) << 4)) = hv[it];
            }
            if (tid < 64) {
                int row = tid >> 2, s = 64 + (tid & 3);
                *(f32x4*)(Atile + row * 1152 + ((s ^ (row & 7)) << 4)) = sv;
            }
        }
        __syncthreads();

        // ---- MFMA: z[16 rows][32 cols] for gate w ----
        f32x4 acc0 = (f32x4){0.f,0.f,0.f,0.f};
        f32x4 acc1 = (f32x4){0.f,0.f,0.f,0.f};
        #pragma unroll
        for (int kc = 0; kc < 17; ++kc) {
            int swz = ((kc * 4 + l4) ^ swzA) << 4;
            bf16x8 a = *(const bf16x8*)(Atile + l15 * 1152 + swz);
            acc0 = __builtin_amdgcn_mfma_f32_16x16x32_bf16(a, bw[0][kc], acc0, 0, 0, 0);
            acc1 = __builtin_amdgcn_mfma_f32_16x16x32_bf16(a, bw[1][kc], acc1, 0, 0, 0);
        }

        // ---- gate exchange: z -> LDS (C/D: col=lane&15, row=(lane>>4)*4+reg) ----
        #pragma unroll
        for (int r = 0; r < 4; ++r) {
            zbuf[w][l4 * 4 + r][l15]      = acc0[r];
            zbuf[w][l4 * 4 + r][16 + l15] = acc1[r];
        }
        __syncthreads();

        // ---- epilogue: 1 row x 2 cols per thread ----
        unsigned hp;
        {
            f32x2 zi2 = *(const f32x2*)(&zbuf[0][rr][c0]);
            f32x2 zf2 = *(const f32x2*)(&zbuf[1][rr][c0]);
            f32x2 zg2 = *(const f32x2*)(&zbuf[2][rr][c0]);
            f32x2 zo2 = *(const f32x2*)(&zbuf[3][rr][c0]);
            float c0n = sigm(zf2[0] + bf0) * creg0 + sigm(zi2[0] + bi0) * ftanh(zg2[0] + bg0);
            float c1n = sigm(zf2[1] + bf1) * creg1 + sigm(zi2[1] + bi1) * ftanh(zg2[1] + bg1);
            creg0 = c0n; creg1 = c1n;
            float h0 = sigm(zo2[0] + bo0) * ftanh(c0n);
            float h1 = sigm(zo2[1] + bo1) * ftanh(c1n);
            hp = (unsigned)f2bfu(h0) | ((unsigned)f2bfu(h1) << 16);
            __hip_bfloat16* hdst = hbuf + ((size_t)((t + 1) & 1) * 2 + dirv) * 131072;
            store4_coh(hdst + (size_t)browE * 512 + hcol0, hp);
            store4_nt(reinterpret_cast<short*>(Aenc) + ((size_t)browE * 256 + tpos) * 1024 + dirv * 512 + hcol0, hp);
        }

        // ---- group barrier (16 blocks sharing (dir,mt16)), R6 protocol ----
        if (t < 255) {
            asm volatile("s_waitcnt vmcnt(0)" ::: "memory");   // h stores acked at LLC (per wave)
            __syncthreads();                                   // all waves acked
            if (tid == 0) {
                __hip_atomic_fetch_add(ctr, 1u, __ATOMIC_RELAXED, __HIP_MEMORY_SCOPE_AGENT);
                unsigned int target = 16u * (unsigned)(t + 1);
                while (__hip_atomic_load(ctr, __ATOMIC_RELAXED, __HIP_MEMORY_SCOPE_AGENT) < target)
                    __builtin_amdgcn_s_sleep(2);
            }
            __syncthreads();
        }
    }

    // ---- write out final c ----
    {
        float* cd = cbuf + (size_t)dirv * 131072 + (size_t)browE * 512 + hcol0;
        cd[0] = creg0; cd[1] = creg1;
    }
}

// ---------------- decoder cell (single step, KD=1024) ----------------

template<int MT, int KD>
__global__ __launch_bounds__(256)
void dec_cell_kernel(const __hip_bfloat16* __restrict__ Abase,
                     const __hip_bfloat16* __restrict__ BTbase,
                     const float* __restrict__ bias,
                     const float* __restrict__ Cin,
                     float* __restrict__ HdecOut)
{
    constexpr int RB = KD * 2;
    constexpr int MF = MT / 16;
    constexpr int KSTEPS = KD / 32;
    const int strip = blockIdx.x;
    const int mt = blockIdx.y;
    const int tid = threadIdx.x;
    const int w = tid >> 6;
    const int lane = tid & 63;

    __shared__ __align__(16) unsigned char Als[MT * KD * 2];
    __shared__ float zbuf[4][MT][33];

    const __hip_bfloat16* A = Abase + (size_t)(mt * MT) * KD;
    const __hip_bfloat16* BT = BTbase;

    const unsigned char* Ac = (const unsigned char*)A;
    #pragma unroll
    for (int it = 0; it < (MT * KD * 2) / 4096; ++it) {
        int p = it * 4096 + tid * 16;
        int row = p / RB;
        int slot = (p % RB) >> 4;
        int ls = slot ^ (row & 7);
        *(f32x4*)(Als + row * RB + ls * 16) = *(const f32x4*)(Ac + p);
    }
    __syncthreads();

    f32x4 acc[MF][2];
    #pragma unroll
    for (int mf = 0; mf < MF; ++mf)
        #pragma unroll
        for (int nf = 0; nf < 2; ++nf)
            acc[mf][nf] = (f32x4){0.f,0.f,0.f,0.f};

    const int l15 = lane & 15, l4 = lane >> 4;
    #pragma unroll 4
    for (int kc = 0; kc < KSTEPS; ++kc) {
        bf16x8 a[MF], bb[2];
        int kslot = kc * 4 + l4;
        #pragma unroll
        for (int mf = 0; mf < MF; ++mf) {
            int row = mf * 16 + l15;
            a[mf] = *(const bf16x8*)(Als + row * RB + ((kslot ^ (row & 7)) << 4));
        }
        #pragma unroll
        for (int nf = 0; nf < 2; ++nf) {
            int zr = w * 512 + strip * 32 + nf * 16 + l15;
            bb[nf] = *(const bf16x8*)(BT + (size_t)zr * KD + kc * 32 + l4 * 8);
        }
        #pragma unroll
        for (int mf = 0; mf < MF; ++mf)
            #pragma unroll
            for (int nf = 0; nf < 2; ++nf)
                acc[mf][nf] = __builtin_amdgcn_mfma_f32_16x16x32_bf16(a[mf], bb[nf], acc[mf][nf], 0, 0, 0);
    }

    #pragma unroll
    for (int mf = 0; mf < MF; ++mf)
        #pragma unroll
        for (int nf = 0; nf < 2; ++nf)
            #pragma unroll
            for (int r = 0; r < 4; ++r)
                zbuf[w][mf * 16 + l4 * 4 + r][nf * 16 + l15] = acc[mf][nf][r];
    __syncthreads();

    constexpr int NE = MT * 32 / 256;
    #pragma unroll
    for (int e = 0; e < NE; ++e) {
        int idx = e * 256 + tid;
        int r = idx >> 5, col = idx & 31;
        int hcol = strip * 32 + col;
        int brow = mt * MT + r;
        float zi = zbuf[0][r][col] + bias[hcol];
        float zf = zbuf[1][r][col] + bias[512 + hcol];
        float zg = zbuf[2][r][col] + bias[1024 + hcol];
        float zo = zbuf[3][r][col] + bias[1536 + hcol];
        float iv = sigm(zi), fv = sigm(zf), gv = ftanh(zg);
        float cold = Cin[(size_t)brow * 512 + hcol];
        float cnew = fv * cold + iv * gv;
        HdecOut[(size_t)brow * 512 + hcol] = sigm(zo) * ftanh(cnew);
    }
}

// ---------------- generic small GEMM: outF[M][N] = A[M][K](bf16) @ BT[N][K]^T + bias ----------------

__global__ __launch_bounds__(256)
void gemm_kernel(const __hip_bfloat16* __restrict__ A,
                 const __hip_bfloat16* __restrict__ BT,
                 const float* __restrict__ bias,
                 float* __restrict__ outF,
                 int M, int N, int K)
{
    const int tid = threadIdx.x;
    const int wv = tid >> 6, lane = tid & 63;
    const int wr = wv >> 1, wc = wv & 1;
    const int m0 = blockIdx.y * 64, n0 = blockIdx.x * 64;
    const int l15 = lane & 15, l4 = lane >> 4;
    f32x4 acc[2][2];
    #pragma unroll
    for (int i = 0; i < 2; ++i)
        #pragma unroll
        for (int j = 0; j < 2; ++j) acc[i][j] = (f32x4){0.f,0.f,0.f,0.f};
    for (int kc = 0; kc < K / 32; ++kc) {
        bf16x8 a[2], b[2];
        #pragma unroll
        for (int m2 = 0; m2 < 2; ++m2)
            a[m2] = *(const bf16x8*)(A + (size_t)(m0 + wr * 32 + m2 * 16 + l15) * K + kc * 32 + l4 * 8);
        #pragma unroll
        for (int n2 = 0; n2 < 2; ++n2)
            b[n2] = *(const bf16x8*)(BT + (size_t)(n0 + wc * 32 + n2 * 16 + l15) * K + kc * 32 + l4 * 8);
        #pragma unroll
        for (int m2 = 0; m2 < 2; ++m2)
            #pragma unroll
            for (int n2 = 0; n2 < 2; ++n2)
                acc[m2][n2] = __builtin_amdgcn_mfma_f32_16x16x32_bf16(a[m2], b[n2], acc[m2][n2], 0, 0, 0);
    }
    #pragma unroll
    for (int m2 = 0; m2 < 2; ++m2)
        #pragma unroll
        for (int n2 = 0; n2 < 2; ++n2)
            #pragma unroll
            for (int r = 0; r < 4; ++r) {
                int row = m0 + wr * 32 + m2 * 16 + l4 * 4 + r;
                int col = n0 + wc * 32 + n2 * 16 + l15;
                float v = acc[m2][n2][r];
                if (bias) v += bias[col];
                outF[(size_t)row * N + col] = v;
            }
}

// ---------------- attention ----------------

__global__ __launch_bounds__(256)
void attn_kernel(const __hip_bfloat16* __restrict__ Aenc,
                 const float* __restrict__ qh,
                 __hip_bfloat16* __restrict__ Aactx)
{
    const int b = blockIdx.x, tid = threadIdx.x;
    __shared__ float qs[1024];
    __shared__ float sc[256];
    __shared__ float wred[4];
    for (int i = tid; i < 1024; i += 256) qs[i] = qh[(size_t)b * 1024 + i];
    __syncthreads();
    const __hip_bfloat16* ar = Aenc + ((size_t)b * 256 + tid) * 1024;
    float s = 0.f;
    for (int j8 = 0; j8 < 128; ++j8) {
        bf16x8 v = *(const bf16x8*)(ar + j8 * 8);
        #pragma unroll
        for (int e = 0; e < 8; ++e) s += bf2f(v[e]) * qs[j8 * 8 + e];
    }
    float m = s;
    for (int o = 32; o; o >>= 1) m = fmaxf(m, __shfl_xor(m, o));
    if ((tid & 63) == 0) wred[tid >> 6] = m;
    __syncthreads();
    m = fmaxf(fmaxf(wred[0], wred[1]), fmaxf(wred[2], wred[3]));
    __syncthreads();
    float ev = __expf(s - m);
    float ss = ev;
    for (int o = 32; o; o >>= 1) ss += __shfl_xor(ss, o);
    if ((tid & 63) == 0) wred[tid >> 6] = ss;
    __syncthreads();
    float tot = wred[0] + wred[1] + wred[2] + wred[3];
    sc[tid] = ev / tot;
    __syncthreads();
    float a0 = 0, a1 = 0, a2 = 0, a3 = 0;
    for (int t2 = 0; t2 < 256; ++t2) {
        float p = sc[t2];
        s16x4 v = *(const s16x4*)(Aenc + ((size_t)b * 256 + t2) * 1024 + tid * 4);
        a0 += p * bf2f(v[0]); a1 += p * bf2f(v[1]); a2 += p * bf2f(v[2]); a3 += p * bf2f(v[3]);
    }
    __hip_bfloat16* dst = Aactx + (size_t)b * 1024 + tid * 4;
    dst[0] = __float2bfloat16(a0); dst[1] = __float2bfloat16(a1);
    dst[2] = __float2bfloat16(a2); dst[3] = __float2bfloat16(a3);
}

// ---------------- small pack kernels ----------------

__global__ void pack_state_kernel(const __hip_bfloat16* __restrict__ hbuf0,
                                  const float* __restrict__ cbuf,
                                  __hip_bfloat16* __restrict__ Astate,
                                  __hip_bfloat16* __restrict__ Astatec)
{
    int i = blockIdx.x * blockDim.x + threadIdx.x;
    if (i < 262144) {
        int bb = i >> 10, jj = i & 1023;
        int dir = jj >> 9, j = jj & 511;
        size_t src = (size_t)dir * 131072 + bb * 512 + j;
        Astate[i] = hbuf0[src];
        Astatec[i] = __float2bfloat16(cbuf[src]);
    }
}

__global__ void pack_dec_kernel(const float* __restrict__ attnf,
                                const float* __restrict__ sh,
                                __hip_bfloat16* __restrict__ Adec)
{
    int i = blockIdx.x * blockDim.x + threadIdx.x;
    if (i < 262144) {
        int bb = i >> 10, jj = i & 1023;
        float v = (jj < 512) ? attnf[bb * 512 + jj] : sh[bb * 512 + (jj - 512)];
        Adec[i] = __float2bfloat16(v);
    }
}

__global__ void out_kernel(const float* __restrict__ hdec,
                           const float* __restrict__ out_w,
                           const float* __restrict__ out_b,
                           float* __restrict__ out)
{
    int b = blockIdx.x, lane = threadIdx.x;
    float a0 = 0.f, a1 = 0.f;
    for (int h = lane; h < 512; h += 64) {
        float hv = hdec[(size_t)b * 512 + h];
        a0 += hv * out_w[2 * h];
        a1 += hv * out_w[2 * h + 1];
    }
    for (int o = 32; o; o >>= 1) { a0 += __shfl_down(a0, o); a1 += __shfl_down(a1, o); }
    if (lane == 0) { out[2 * b] = a0 + out_b[0]; out[2 * b + 1] = a1 + out_b[1]; }
}

// ---------------- launch ----------------

extern "C" void kernel_launch(void* const* d_in, const int* in_sizes, int n_in,
                              void* d_out, int out_size, void* d_ws, size_t ws_size,
                              hipStream_t stream) {
    (void)in_sizes; (void)n_in; (void)out_size; (void)ws_size;
    const float* x        = (const float*)d_in[0];
    const int*   y_past   = (const int*)d_in[1];
    const float* ln_g     = (const float*)d_in[2];
    const float* ln_b     = (const float*)d_in[3];
    const float* w1       = (const float*)d_in[4];
    const float* b1       = (const float*)d_in[5];
    const float* w2       = (const float*)d_in[6];
    const float* b2       = (const float*)d_in[7];
    const float* w3       = (const float*)d_in[8];
    const float* b3       = (const float*)d_in[9];
    const float* w4       = (const float*)d_in[10];
    const float* b4       = (const float*)d_in[11];
    const float* bn1_g    = (const float*)d_in[12];
    const float* bn1_b    = (const float*)d_in[13];
    const float* bn1_m    = (const float*)d_in[14];
    const float* bn1_v    = (const float*)d_in[15];
    const float* bn2_g    = (const float*)d_in[16];
    const float* bn2_b    = (const float*)d_in[17];
    const float* bn2_m    = (const float*)d_in[18];
    const float* bn2_v    = (const float*)d_in[19];
    const float* efwx     = (const float*)d_in[20];
    const float* efwh     = (const float*)d_in[21];
    const float* efbias   = (const float*)d_in[22];
    const float* ebwx     = (const float*)d_in[23];
    const float* ebwh     = (const float*)d_in[24];
    const float* ebbias   = (const float*)d_in[25];
    const float* dec_wx   = (const float*)d_in[26];
    const float* dec_wh   = (const float*)d_in[27];
    const float* dec_bias = (const float*)d_in[28];
    const float* proj_w   = (const float*)d_in[29];
    const float* proj_b   = (const float*)d_in[30];
    const float* sph_w    = (const float*)d_in[31];
    const float* sph_b    = (const float*)d_in[32];
    const float* spc_w    = (const float*)d_in[33];
    const float* spc_b    = (const float*)d_in[34];
    const float* out_w    = (const float*)d_in[35];
    const float* out_b    = (const float*)d_in[36];

    char* wsb = (char*)d_ws;
    size_t off = 0;
    auto alloc = [&](size_t bytes) -> char* {
        char* r = wsb + off;
        off = (off + bytes + 255) & ~(size_t)255;
        return r;
    };
    __hip_bfloat16* BTcat   = (__hip_bfloat16*)alloc(2ull * 2048 * 544 * 2);   // [dir][2048][544]
    __hip_bfloat16* decT    = (__hip_bfloat16*)alloc(2048ull * 1024 * 2);      // [2048][1024]
    __hip_bfloat16* projT   = (__hip_bfloat16*)alloc(512ull * 1024 * 2);       // [512][1024]
    __hip_bfloat16* projWb  = (__hip_bfloat16*)alloc(1024ull * 512 * 2);       // [1024][512]
    __hip_bfloat16* sphT    = (__hip_bfloat16*)alloc(512ull * 1024 * 2);
    __hip_bfloat16* spcT    = (__hip_bfloat16*)alloc(512ull * 1024 * 2);
    __hip_bfloat16* w1T     = (__hip_bfloat16*)alloc(128ull * 512 * 2);        // [128][512]
    __hip_bfloat16* w2T     = (__hip_bfloat16*)alloc(64ull * 128 * 2);         // [64][128]
    float*          biasz   = (float*)alloc(2ull * 2048 * 4);
    __hip_bfloat16* seqbf   = (__hip_bfloat16*)alloc(256ull * 256 * 32 * 2);   // [T][B][32]
    __hip_bfloat16* hbuf    = (__hip_bfloat16*)alloc(2ull * 2 * 256 * 512 * 2);// [par][dir][B][H]
    float*          cbuf    = (float*)alloc(2ull * 256 * 512 * 4);             // [dir][B][H]
    __hip_bfloat16* Aenc    = (__hip_bfloat16*)alloc(65536ull * 1024 * 2);     // [B*T][2H]
    unsigned int*   ctrs    = (unsigned int*)alloc(32ull * 32 * 4);            // group barrier counters
    __hip_bfloat16* Astate  = (__hip_bfloat16*)alloc(256ull * 1024 * 2);
    __hip_bfloat16* Astatec = (__hip_bfloat16*)alloc(256ull * 1024 * 2);
    float*          state_h = (float*)alloc(256ull * 512 * 4);
    float*          state_c = (float*)alloc(256ull * 512 * 4);
    __hip_bfloat16* Ash     = (__hip_bfloat16*)alloc(256ull * 512 * 2);
    float*          qh      = (float*)alloc(256ull * 1024 * 4);
    __hip_bfloat16* Aactx   = (__hip_bfloat16*)alloc(256ull * 1024 * 2);
    float*          attnf   = (float*)alloc(256ull * 512 * 4);
    __hip_bfloat16* Adec    = (__hip_bfloat16*)alloc(256ull * 1024 * 2);
    float*          hdec    = (float*)alloc(256ull * 512 * 4);

    // ---- weight prep: one batched tiled-transpose launch ----
    (void)hipMemsetAsync(BTcat, 0, 2ull * 2048 * 544 * 2, stream);   // zero K-pad cols
    {
        TransJobs jobs;
        jobs.src[0]  = efwh;   jobs.dst[0]  = BTcat;              jobs.K[0]  = 512;  jobs.N[0]  = 2048; jobs.kOff[0]  = 0;   jobs.KD[0]  = 544;
        jobs.src[1]  = efwx;   jobs.dst[1]  = BTcat;              jobs.K[1]  = 17;   jobs.N[1]  = 2048; jobs.kOff[1]  = 512; jobs.KD[1]  = 544;
        jobs.src[2]  = ebwh;   jobs.dst[2]  = BTcat + 2048 * 544; jobs.K[2]  = 512;  jobs.N[2]  = 2048; jobs.kOff[2]  = 0;   jobs.KD[2]  = 544;
        jobs.src[3]  = ebwx;   jobs.dst[3]  = BTcat + 2048 * 544; jobs.K[3]  = 17;   jobs.N[3]  = 2048; jobs.kOff[3]  = 512; jobs.KD[3]  = 544;
        jobs.src[4]  = proj_w; jobs.dst[4]  = projT;              jobs.K[4]  = 1024; jobs.N[4]  = 512;  jobs.kOff[4]  = 0;   jobs.KD[4]  = 1024;
        jobs.src[5]  = sph_w;  jobs.dst[5]  = sphT;               jobs.K[5]  = 1024; jobs.N[5]  = 512;  jobs.kOff[5]  = 0;   jobs.KD[5]  = 1024;
        jobs.src[6]  = spc_w;  jobs.dst[6]  = spcT;               jobs.K[6]  = 1024; jobs.N[6]  = 512;  jobs.kOff[6]  = 0;   jobs.KD[6]  = 1024;
        jobs.src[7]  = dec_wx; jobs.dst[7]  = decT;               jobs.K[7]  = 512;  jobs.N[7]  = 2048; jobs.kOff[7]  = 0;   jobs.KD[7]  = 1024;
        jobs.src[8]  = dec_wh; jobs.dst[8]  = decT;               jobs.K[8]  = 512;  jobs.N[8]  = 2048; jobs.kOff[8]  = 512; jobs.KD[8]  = 1024;
        jobs.src[9]  = w1;     jobs.dst[9]  = w1T;                jobs.K[9]  = 512;  jobs.N[9]  = 128;  jobs.kOff[9]  = 0;   jobs.KD[9]  = 512;
        jobs.src[10] = w2;     jobs.dst[10] = w2T;                jobs.K[10] = 128;  jobs.N[10] = 64;   jobs.kOff[10] = 0;   jobs.KD[10] = 128;
        trans_tiled_kernel<<<dim3(1024, NTJOBS), 256, 0, stream>>>(jobs);
    }
    cvt_f2b_kernel<<<1024, 256, 0, stream>>>(projWb, proj_w, 1024 * 512);
    copy_f_kernel<<<8, 256, 0, stream>>>(biasz, efbias, 2048);
    copy_f_kernel<<<8, 256, 0, stream>>>(biasz + 2048, ebbias, 2048);

    (void)hipMemsetAsync(hbuf, 0, 2ull * 256 * 512 * 2, stream);      // parity-0 h = 0
    (void)hipMemsetAsync(ctrs, 0, 32ull * 32 * 4, stream);            // barrier counters = 0

    // ---- funnel ----
    funnel_kernel<<<4096, 256, 0, stream>>>(x, y_past, ln_g, ln_b,
        w1T, b1, w2T, b2, w3, b3, w4, b4,
        bn1_g, bn1_b, bn1_m, bn1_v, bn2_g, bn2_b, bn2_m, bn2_v, seqbf);

    // ---- persistent bidirectional LSTM: 512 blocks (2/CU), all resident by sizing ----
    lstm_persistent<<<dim3(512), dim3(256), 0, stream>>>(
        BTcat, biasz, seqbf, hbuf, cbuf, Aenc, ctrs);

    // ---- states ----
    pack_state_kernel<<<1024, 256, 0, stream>>>(hbuf, cbuf, Astate, Astatec);
    gemm_kernel<<<dim3(8, 4), 256, 0, stream>>>(Astate, sphT, sph_b, state_h, 256, 512, 1024);
    gemm_kernel<<<dim3(8, 4), 256, 0, stream>>>(Astatec, spcT, spc_b, state_c, 256, 512, 1024);
    cvt_f2b_kernel<<<512, 256, 0, stream>>>(Ash, state_h, 256 * 512);

    // ---- attention (proj folded out): qh = state_h @ proj_w^T ----
    gemm_kernel<<<dim3(16, 4), 256, 0, stream>>>(Ash, projWb, nullptr, qh, 256, 1024, 512);
    attn_kernel<<<256, 256, 0, stream>>>(Aenc, qh, Aactx);
    gemm_kernel<<<dim3(8, 4), 256, 0, stream>>>(Aactx, projT, proj_b, attnf, 256, 512, 1024);

    // ---- decoder cell ----
    pack_dec_kernel<<<1024, 256, 0, stream>>>(attnf, state_h, Adec);
    dec_cell_kernel<32, 1024><<<dim3(16, 8), 256, 0, stream>>>(
        Adec, decT, dec_bias, state_c, hdec);

    // ---- output ----
    out_kernel<<<256, 64, 0, stream>>>(hdec, out_w, out_b, (float*)d_out);
}